// Round 1
// 148.666 us; speedup vs baseline: 1.0004x; 1.0004x over previous
//
#include <hip/hip_runtime.h>

// 2-bit quantized embedding gather — wave-autonomous version.
// VOCAB=400000, DIM=128, NBITS=2 -> token t owns 8 aligned int32 words
// bit_arr[8t..8t+7] (32B row); dim d -> word 8t + d/16; 2-bit code;
// out = codebook[code].
//
// History: fused 1-thread/item 166.7us (R1) -> split via ws 152.5 (R4)
// -> block LDS staging 148.7 (R6). R6 counters: fill kernels write 512MiB
// at 6.6 TB/s (80us) while we move ~150MB in 148us (~1 TB/s) -> we are 6x
// under the write roofline; latency/barrier-serialized, not BW-bound.
//
// R7 (this): wave-autonomous, barrier-free. Each wave gathers its own 32
// token rows (1KB) into its private LDS quarter via async global_load_lds
// (width=16, per-lane random source addr, lane-ordered LDS dest — m104
// contract), one s_waitcnt vmcnt(0), NO s_barrier (producer wave ==
// consumer wave), then decodes 16 float4/lane into one contiguous 16KB
// chunk. All 4 waves do useful work in both phases; 2048 blocks; tiny
// VGPR + 4KB LDS -> full 32 waves/CU; no inter-wave coupling left.

#define EMB_DIM 128
#define TOK_PER_WAVE 32
#define WAVES_PER_BLOCK 4
#define TOK_PER_BLOCK (TOK_PER_WAVE * WAVES_PER_BLOCK)   // 128
#define BLOCK 256

typedef float vfloat4 __attribute__((ext_vector_type(4)));

__global__ __launch_bounds__(BLOCK) void embed2bit_wave_kernel(
    const int* __restrict__ ids,      // [n_tokens] int32
    const int* __restrict__ bits,     // [3,200,000] packed int32
    const float* __restrict__ cb,     // [4] codebook
    float* __restrict__ out,          // [n_tokens, 128] fp32
    int n_tokens)
{
    __shared__ int lds_words[TOK_PER_BLOCK * 8];   // 4 KB: 1 KB per wave

    const int tid  = threadIdx.x;
    const int w    = tid >> 6;
    const int lane = tid & 63;

    const int tile = blockIdx.x * WAVES_PER_BLOCK + w;   // wave-tile id
    const int tb   = tile * TOK_PER_WAVE;                // first token
    if (tb >= n_tokens) return;                          // whole-wave exit, no barrier below
    const int tleft = n_tokens - tb;
    const int ntok  = tleft < TOK_PER_WAVE ? tleft : TOK_PER_WAVE;

    // --- Phase 1: this wave gathers its 32 token rows (1 KB) into its own
    // LDS quarter. 2 lanes per token, 16B per lane, async direct-to-LDS.
    int* lds_w = lds_words + w * (TOK_PER_WAVE * 8);
    const int myTok = lane >> 1;
    if (myTok < ntok) {
        int tok = ids[tb + myTok];                       // 2 lanes broadcast
        __builtin_amdgcn_global_load_lds(
            (const __attribute__((address_space(1))) void*)
                (bits + (long long)tok * 8 + (lane & 1) * 4),
            (__attribute__((address_space(3))) void*)(lds_w + lane * 4),
            16, 0, 0);                                   // 16B/lane, lane-ordered dest
    }
    asm volatile("s_waitcnt vmcnt(0)" ::: "memory");
    // no __syncthreads(): producer wave == consumer wave.

    // --- Phase 2: decode 1024 items (32 tokens x 32 float4) = 16/lane,
    // one contiguous 16 KB store range per wave.
    const float c0 = cb[0], c1 = cb[1], c2 = cb[2], c3 = cb[3];
    const long long out_base = (long long)tb * EMB_DIM;
    const int n_items = ntok * 32;

#pragma unroll
    for (int q = 0; q < 16; ++q) {
        int item = q * 64 + lane;                 // [0, 1024)
        if (item >= n_items) break;
        int word = lds_w[item >> 2];              // 4 lanes broadcast a word
        int byte = (word >> ((item & 3) * 8)) & 0xff;

        vfloat4 r;
#pragma unroll
        for (int j = 0; j < 4; ++j) {
            int c    = (byte >> (2 * j)) & 3;
            float lo = (c & 1) ? c1 : c0;
            float hi = (c & 1) ? c3 : c2;
            r[j]     = (c & 2) ? hi : lo;         // 2x v_cndmask per element
        }
        // consecutive lanes -> contiguous 1 KB per wave-store.
        *reinterpret_cast<vfloat4*>(out + out_base + (long long)item * 4) = r;
    }
}

extern "C" void kernel_launch(void* const* d_in, const int* in_sizes, int n_in,
                              void* d_out, int out_size, void* d_ws, size_t ws_size,
                              hipStream_t stream) {
    const int*   ids  = (const int*)d_in[0];
    const int*   bits = (const int*)d_in[1];
    const float* cb   = (const float*)d_in[2];
    float*       out  = (float*)d_out;

    int n_tokens = in_sizes[0];                   // 262,144
    int grid = (n_tokens + TOK_PER_BLOCK - 1) / TOK_PER_BLOCK;   // 2048

    embed2bit_wave_kernel<<<grid, BLOCK, 0, stream>>>(ids, bits, cb, out, n_tokens);
}